// Round 6
// baseline (226.341 us; speedup 1.0000x reference)
//
#include <hip/hip_runtime.h>
#include <hip/hip_bf16.h>
#include <math.h>

#define B_ 2
#define N_ 2048
#define C_ 1024
#define H_ 16
#define G_ 4
#define D_ 64

using short8  = __attribute__((ext_vector_type(8))) short;
using float4v = __attribute__((ext_vector_type(4))) float;

__device__ __forceinline__ ushort f2bf(float f) {
    union { float f; unsigned u; } v; v.f = f;
    unsigned r = (v.u + 0x7FFF + ((v.u >> 16) & 1)) >> 16;  // RNE
    return (ushort)r;
}
__device__ __forceinline__ float bf2f(ushort u) {
    union { unsigned u; float f; } t; t.u = ((unsigned)u) << 16; return t.f;
}
__device__ __forceinline__ unsigned pack_bf16(float a, float b) {
#if __has_builtin(__builtin_amdgcn_cvt_pk_bf16_f32)
    auto t = __builtin_amdgcn_cvt_pk_bf16_f32(a, b);
    unsigned r; __builtin_memcpy(&r, &t, 4); return r;
#else
    return (unsigned)f2bf(a) | ((unsigned)f2bf(b) << 16);
#endif
}
__device__ __forceinline__ float fexp2(float x) {
#if __has_builtin(__builtin_amdgcn_exp2f)
    return __builtin_amdgcn_exp2f(x);
#else
    return exp2f(x);
#endif
}

// ---------------------------------------------------------------------------
// x fp32 -> bf16
// ---------------------------------------------------------------------------
__global__ void convert_x(const float* __restrict__ x, ushort* __restrict__ xb) {
    int i = (blockIdx.x * 256 + threadIdx.x) * 4;
    float4 v = *(const float4*)(x + i);
    ushort4 o;
    o.x = f2bf(v.x); o.y = f2bf(v.y); o.z = f2bf(v.z); o.w = f2bf(v.w);
    *(ushort4*)(xb + i) = o;
}

// ---------------------------------------------------------------------------
// Transpose-convert: src [K][N] fp32 -> dst [N][K] bf16
// ---------------------------------------------------------------------------
__global__ void tconv(const float* __restrict__ src, ushort* __restrict__ dst,
                      int K, int N) {
    __shared__ float T[64][65];
    const int n0 = blockIdx.x * 64, k0 = blockIdx.y * 64;
    const int tid = threadIdx.x;
    #pragma unroll
    for (int s = 0; s < 16; ++s) {
        int idx = tid + s * 256; int r = idx >> 6, cc = idx & 63;
        T[r][cc] = src[(size_t)(k0 + r) * N + n0 + cc];
    }
    __syncthreads();
    #pragma unroll
    for (int s = 0; s < 16; ++s) {
        int idx = tid + s * 256; int r = idx >> 6, cc = idx & 63;
        dst[(size_t)(n0 + r) * K + k0 + cc] = f2bf(T[cc][r]);
    }
}

// ---------------------------------------------------------------------------
// bf16 MFMA GEMM, 128x64 tile (M x N), BK=32, global_load_lds(16) staging,
// 2-barrier K-loop. C[M][N] = A[M][K] @ Bt[N][K]^T.
// Wave w owns rows w*32..w*32+31 x all 64 cols: 8 MFMA per 6 ds_read_b128.
// ---------------------------------------------------------------------------
template <bool F32OUT>
__global__ __launch_bounds__(256) void gemm128x64(const ushort* __restrict__ A,
                                                  const ushort* __restrict__ Bt,
                                                  void* __restrict__ Cv,
                                                  int M, int N, int K) {
    __shared__ __align__(16) ushort As[128 * 32];   // 64 B rows (m97 layout)
    __shared__ __align__(16) ushort Bs[64 * 32];

    const int tid = threadIdx.x, wave = tid >> 6, lane = tid & 63;
    const int g = lane >> 4, c = lane & 15;
    const int m0 = blockIdx.y * 128, n0 = blockIdx.x * 64;

    // staging: each global_load_lds covers 16 rows (4 lanes/row, 16B chunks)
    const int srow = lane >> 2, schunk = (lane & 3) * 8;
    const ushort* paA0 = A  + (size_t)(m0 + wave * 32 + srow) * K + schunk;
    const ushort* paA1 = A  + (size_t)(m0 + wave * 32 + 16 + srow) * K + schunk;
    const ushort* paB  = Bt + (size_t)(n0 + wave * 16 + srow) * K + schunk;
    ushort* ldsA0 = &As[(wave * 32) * 32];
    ushort* ldsA1 = &As[(wave * 32 + 16) * 32];
    ushort* ldsB  = &Bs[(wave * 16) * 32];

    float4v acc[2][4];
    #pragma unroll
    for (int a = 0; a < 2; ++a)
        #pragma unroll
        for (int n = 0; n < 4; ++n) acc[a][n] = {0, 0, 0, 0};

    for (int k0 = 0; k0 < K; k0 += 32) {
        __builtin_amdgcn_global_load_lds(
            (const __attribute__((address_space(1))) void*)(paA0 + k0),
            (__attribute__((address_space(3))) void*)ldsA0, 16, 0, 0);
        __builtin_amdgcn_global_load_lds(
            (const __attribute__((address_space(1))) void*)(paA1 + k0),
            (__attribute__((address_space(3))) void*)ldsA1, 16, 0, 0);
        __builtin_amdgcn_global_load_lds(
            (const __attribute__((address_space(1))) void*)(paB + k0),
            (__attribute__((address_space(3))) void*)ldsB, 16, 0, 0);
        __syncthreads();

        short8 af0 = *(const short8*)&As[(wave * 32 + c) * 32 + 8 * g];
        short8 af1 = *(const short8*)&As[(wave * 32 + 16 + c) * 32 + 8 * g];
        #pragma unroll
        for (int n = 0; n < 4; ++n) {
            short8 bfn = *(const short8*)&Bs[(n * 16 + c) * 32 + 8 * g];
            acc[0][n] = __builtin_amdgcn_mfma_f32_16x16x32_bf16(af0, bfn, acc[0][n], 0, 0, 0);
            acc[1][n] = __builtin_amdgcn_mfma_f32_16x16x32_bf16(af1, bfn, acc[1][n], 0, 0, 0);
        }
        __syncthreads();
    }

    #pragma unroll
    for (int a = 0; a < 2; ++a)
        #pragma unroll
        for (int n = 0; n < 4; ++n)
            #pragma unroll
            for (int r = 0; r < 4; ++r) {
                int rowi = m0 + wave * 32 + a * 16 + 4 * g + r;
                int coli = n0 + n * 16 + c;
                if (F32OUT) ((float*)Cv)[(size_t)rowi * N + coli] = acc[a][n][r];
                else ((ushort*)Cv)[(size_t)rowi * N + coli] = f2bf(acc[a][n][r]);
            }
}

// ---------------------------------------------------------------------------
// qkvb [M][1536] bf16 -> Kt[b][j][d] (rope(sum_g k_g)), VtT[b][d][j'] (sum_g v),
// j' = key-permuted within 32-chunks (matches attn P-pack order).
// ---------------------------------------------------------------------------
__global__ void kv_reduce2(const ushort* __restrict__ qkvb,
                           ushort* __restrict__ Kt, ushort* __restrict__ VtT) {
    const int wid = threadIdx.x >> 6, d = threadIdx.x & 63;
    const int rowg = blockIdx.x * 4 + wid;          // b*N + n
    const int n = rowg & (N_ - 1), b = rowg >> 11;

    const ushort* base = qkvb + (size_t)rowg * 1536 + 1024;
    float ks = 0.f, vs = 0.f;
    #pragma unroll
    for (int g = 0; g < G_; ++g) {
        ks += bf2f(base[g * 64 + d]);
        vs += bf2f(base[256 + g * 64 + d]);
    }
    float partner = __shfl_xor(ks, 32, 64);
    float rh = (d < 32) ? -partner : partner;
    float ang = (float)n * __powf(10000.0f, -(float)(d & 31) * (1.0f / 32.0f));
    float sn, cs; __sincosf(ang, &sn, &cs);

    Kt[(size_t)rowg * 64 + d] = f2bf(ks * cs + rh * sn);
    int jp = (n & ~31) | (((n & 15) << 1) | ((n >> 4) & 1));
    VtT[((size_t)b * 64 + d) * N_ + jp] = f2bf(vs);
}

// ---------------------------------------------------------------------------
// Flash attention v6: 4 waves x 64 Q-rows, K-split x2, DOUBLE-BUFFERED
// global_load_lds staging (1 barrier/tile, DMA overlaps prev-tile compute),
// per-row-group P bounce (5 KB Psh), l via ones-MFMA.
// ---------------------------------------------------------------------------
#define PS 40
#define QSCALE 0.18033688011112042f   // 0.125 * log2(e)

__global__ __launch_bounds__(256) void attn6(
        const ushort* __restrict__ qkvb, const ushort* __restrict__ Kt,
        const ushort* __restrict__ VtT,
        ushort* __restrict__ oP0, ushort* __restrict__ oP1,
        float* __restrict__ lP0, float* __restrict__ lP1) {
    const int s  = blockIdx.x & 1;
    const int qt = (blockIdx.x >> 1) & 7;
    const int h  = (blockIdx.x >> 4) & 15;
    const int b  = blockIdx.x >> 8;
    const int tid = threadIdx.x, wave = tid >> 6, lane = tid & 63;
    const int g = lane >> 4, c = lane & 15;

    __shared__ __align__(16) ushort Ksh[2][64 * 64];  // 128 B rows, XOR-swizzled
    __shared__ __align__(16) ushort Vsh[2][64 * 64];
    __shared__ __align__(16) ushort Psh[4][16 * PS];  // per-wave, per-row-group

    ushort* oPs = s ? oP1 : oP0;
    float*  lPs = s ? lP1 : lP0;

    const int i0 = qt * 256 + wave * 64;
    // Q prologue: RoPE + scale (d<->d+32 partner = register pair)
    short8 qf[4][2];
    #pragma unroll
    for (int a = 0; a < 4; ++a) {
        const int row = i0 + a * 16 + c;
        const ushort* qrow = qkvb + (size_t)(b * N_ + row) * 1536 + h * 64;
        short8 raw0 = *(const short8*)(qrow + 8 * g);
        short8 raw1 = *(const short8*)(qrow + 32 + 8 * g);
        #pragma unroll
        for (int i = 0; i < 8; ++i) {
            int dd = 8 * g + i;
            float f0 = bf2f((ushort)raw0[i]), f1 = bf2f((ushort)raw1[i]);
            float ang = (float)row * __powf(10000.0f, -(float)dd * (1.0f / 32.0f));
            float sn, cs; __sincosf(ang, &sn, &cs);
            qf[a][0][i] = (short)f2bf((f0 * cs - f1 * sn) * QSCALE);
            qf[a][1][i] = (short)f2bf((f1 * cs + f0 * sn) * QSCALE);
        }
    }

    const short8 ones = {(short)0x3F80, (short)0x3F80, (short)0x3F80, (short)0x3F80,
                         (short)0x3F80, (short)0x3F80, (short)0x3F80, (short)0x3F80};

    float4v o[4][4];
    float4v o4[4];
    #pragma unroll
    for (int a = 0; a < 4; ++a) {
        o4[a] = {0, 0, 0, 0};
        #pragma unroll
        for (int f = 0; f < 4; ++f) o[a][f] = {0, 0, 0, 0};
    }

    const ushort* Kb = Kt  + (size_t)b * N_ * 64;
    const ushort* Vb = VtT + (size_t)b * 64 * N_;
    const int lr8 = lane >> 3, lq8 = lane & 7;
    const int swz = (lq8 ^ lr8) * 8;                 // XOR chunk swizzle
    const int j0 = s * (N_ / 2);
    const int NT = (N_ / 2) / 64;                    // 16 tiles

    // stage tile (64 keys at j) into buffer bi: 2 K-instrs + 2 V-instrs / wave
    auto stage = [&](int j, int bi) {
        #pragma unroll
        for (int t = 0; t < 2; ++t) {
            const int row8 = wave * 16 + t * 8;
            __builtin_amdgcn_global_load_lds(
                (const __attribute__((address_space(1))) void*)
                    (Kb + (size_t)(j + row8 + lr8) * 64 + swz),
                (__attribute__((address_space(3))) void*)&Ksh[bi][row8 * 64], 16, 0, 0);
            __builtin_amdgcn_global_load_lds(
                (const __attribute__((address_space(1))) void*)
                    (Vb + (size_t)(row8 + lr8) * N_ + j + swz),
                (__attribute__((address_space(3))) void*)&Vsh[bi][row8 * 64], 16, 0, 0);
        }
    };

    stage(j0, 0);   // preload tile 0

    for (int t = 0; t < NT; ++t) {
        __syncthreads();                     // drains DMA for buf[t&1]; WAR-safe
        if (t + 1 < NT) stage(j0 + (t + 1) * 64, (t + 1) & 1);
        const ushort* Kc = Ksh[t & 1];
        const ushort* Vc = Vsh[t & 1];

        #pragma unroll
        for (int jj = 0; jj < 64; jj += 32) {
            // ---- scores
            float4v sc[4][2];
            #pragma unroll
            for (int tt = 0; tt < 2; ++tt) {
                const int R = jj + 16 * tt + c;
                short8 ka = *(const short8*)&Kc[R * 64 + ((g ^ (c & 7)) * 8)];
                short8 kb = *(const short8*)&Kc[R * 64 + (((g ^ 4) ^ (c & 7)) * 8)];
                #pragma unroll
                for (int a = 0; a < 4; ++a) {
                    if (tt == 0) { sc[a][0] = {0,0,0,0}; sc[a][1] = {0,0,0,0}; }
                    sc[a][tt] = __builtin_amdgcn_mfma_f32_16x16x32_bf16(qf[a][0], ka, sc[a][tt], 0, 0, 0);
                    sc[a][tt] = __builtin_amdgcn_mfma_f32_16x16x32_bf16(qf[a][1], kb, sc[a][tt], 0, 0, 0);
                }
            }
            // ---- per row-group: exp2, pack, bounce, PV + ones
            const int vb = (jj >> 3);        // 0 or 4
            #pragma unroll
            for (int a = 0; a < 4; ++a) {
                #pragma unroll
                for (int r = 0; r < 4; ++r) {
                    float p0 = fexp2(sc[a][0][r]), p1 = fexp2(sc[a][1][r]);
                    ((unsigned*)&Psh[wave][(4 * g + r) * PS])[c] = pack_bf16(p0, p1);
                }
                short8 pf = *(const short8*)&Psh[wave][c * PS + 8 * g];
                #pragma unroll
                for (int f = 0; f < 4; ++f) {
                    const int R = 16 * f + c;
                    short8 vf = *(const short8*)&Vc[R * 64 + (((g ^ vb) ^ (c & 7)) * 8)];
                    o[a][f] = __builtin_amdgcn_mfma_f32_16x16x32_bf16(pf, vf, o[a][f], 0, 0, 0);
                }
                o4[a] = __builtin_amdgcn_mfma_f32_16x16x32_bf16(pf, ones, o4[a], 0, 0, 0);
            }
        }
    }

    // epilogue: unnormalized bf16 o + fp32 l partials
    #pragma unroll
    for (int a = 0; a < 4; ++a)
        #pragma unroll
        for (int r = 0; r < 4; ++r) {
            const int row = i0 + a * 16 + 4 * g + r;
            if (c == 0) lPs[(size_t)(b * N_ + row) * 16 + h] = o4[a][r];
            size_t base = (size_t)(b * N_ + row) * 1024 + h * 64 + c;
            oPs[base]      = f2bf(o[a][0][r]);
            oPs[base + 16] = f2bf(o[a][1][r]);
            oPs[base + 32] = f2bf(o[a][2][r]);
            oPs[base + 48] = f2bf(o[a][3][r]);
        }
}

// ---------------------------------------------------------------------------
// Combine: ao = (oP0 + oP1) / (lP0 + lP1), bf16 out (in-place over oP0 ok)
// ---------------------------------------------------------------------------
__global__ void combine(const ushort* __restrict__ oP0, const ushort* __restrict__ oP1,
                        const float* __restrict__ lP0, const float* __restrict__ lP1,
                        ushort* __restrict__ ao) {
    const int e = (blockIdx.x * 256 + threadIdx.x) * 4;
    const int row = e >> 10, hh = (e >> 6) & 15;
    const float inv = 1.0f / (lP0[row * 16 + hh] + lP1[row * 16 + hh]);
    ushort4 a = *(const ushort4*)(oP0 + e);
    ushort4 b = *(const ushort4*)(oP1 + e);
    ushort4 r;
    r.x = f2bf((bf2f(a.x) + bf2f(b.x)) * inv);
    r.y = f2bf((bf2f(a.y) + bf2f(b.y)) * inv);
    r.z = f2bf((bf2f(a.z) + bf2f(b.z)) * inv);
    r.w = f2bf((bf2f(a.w) + bf2f(b.w)) * inv);
    *(ushort4*)(ao + e) = r;
}

// ---------------------------------------------------------------------------
extern "C" void kernel_launch(void* const* d_in, const int* in_sizes, int n_in,
                              void* d_out, int out_size, void* d_ws, size_t ws_size,
                              hipStream_t stream) {
    const float* x     = (const float*)d_in[0];
    const float* w_q   = (const float*)d_in[1];
    const float* w_kv  = (const float*)d_in[2];
    const float* w_out = (const float*)d_in[3];
    float* out = (float*)d_out;

    const int M = B_ * N_;                               // 4096
    ushort* xb    = (ushort*)d_ws;                       // 4096*1024  (-> oP0 -> ao)
    ushort* wqkvT = xb    + (size_t)M * C_;              // 1536*1024
    ushort* woutT = wqkvT + (size_t)1536 * C_;           // 1024*1024
    ushort* qkvb  = woutT + (size_t)C_ * C_;             // 4096*1536
    ushort* Kt    = qkvb  + (size_t)M * 1536;            // 2*2048*64
    ushort* VtT   = Kt    + (size_t)B_ * N_ * D_;        // 2*64*2048
    ushort* oP1   = VtT   + (size_t)B_ * D_ * N_;        // 4096*1024 bf16 partial
    float*  lP0   = (float*)(oP1 + (size_t)M * C_);      // 4096*16 fp32
    float*  lP1   = lP0 + (size_t)M * H_;
    ushort* oP0   = xb;   // xb dead after qkv GEMM
    ushort* ao    = xb;   // combine writes in-place over oP0

    convert_x<<<(M * C_) / 1024, 256, 0, stream>>>(x, xb);
    tconv<<<dim3(16, 16), 256, 0, stream>>>(w_q,  wqkvT,                   C_, C_);
    tconv<<<dim3(8, 16),  256, 0, stream>>>(w_kv, wqkvT + (size_t)C_ * C_, C_, 2 * G_ * D_);
    tconv<<<dim3(16, 16), 256, 0, stream>>>(w_out, woutT,                  C_, C_);

    gemm128x64<false><<<dim3(1536 / 64, M / 128), 256, 0, stream>>>(xb, wqkvT, qkvb, M, 1536, C_);
    kv_reduce2<<<M / 4, 256, 0, stream>>>(qkvb, Kt, VtT);
    attn6<<<B_ * H_ * (N_ / 256) * 2, 256, 0, stream>>>(qkvb, Kt, VtT, oP0, oP1, lP0, lP1);
    combine<<<(M * C_) / 1024, 256, 0, stream>>>(oP0, oP1, lP0, lP1, ao);
    gemm128x64<true><<<dim3(C_ / 64, M / 128), 256, 0, stream>>>(ao, woutT, out, M, C_, C_);
}

// Round 7
// 196.783 us; speedup vs baseline: 1.1502x; 1.1502x over previous
//
#include <hip/hip_runtime.h>
#include <hip/hip_bf16.h>
#include <math.h>

#define B_ 2
#define N_ 2048
#define C_ 1024
#define H_ 16
#define G_ 4
#define D_ 64

using short8  = __attribute__((ext_vector_type(8))) short;
using short4v = __attribute__((ext_vector_type(4))) short;
using float4v = __attribute__((ext_vector_type(4))) float;

#if __has_builtin(__builtin_amdgcn_mfma_f32_16x16x16_bf16)
#define MFMA16K16(A, B, C) __builtin_amdgcn_mfma_f32_16x16x16_bf16(A, B, C, 0, 0, 0)
#else
#define MFMA16K16(A, B, C) __builtin_amdgcn_mfma_f32_16x16x16bf16_1k(A, B, C, 0, 0, 0)
#endif

__device__ __forceinline__ ushort f2bf(float f) {
    union { float f; unsigned u; } v; v.f = f;
    unsigned r = (v.u + 0x7FFF + ((v.u >> 16) & 1)) >> 16;  // RNE
    return (ushort)r;
}
__device__ __forceinline__ float bf2f(ushort u) {
    union { unsigned u; float f; } t; t.u = ((unsigned)u) << 16; return t.f;
}
__device__ __forceinline__ unsigned pack_bf16(float a, float b) {
#if __has_builtin(__builtin_amdgcn_cvt_pk_bf16_f32)
    auto t = __builtin_amdgcn_cvt_pk_bf16_f32(a, b);
    unsigned r; __builtin_memcpy(&r, &t, 4); return r;
#else
    return (unsigned)f2bf(a) | ((unsigned)f2bf(b) << 16);
#endif
}
__device__ __forceinline__ float fexp2(float x) {
#if __has_builtin(__builtin_amdgcn_exp2f)
    return __builtin_amdgcn_exp2f(x);
#else
    return exp2f(x);
#endif
}

// ---------------------------------------------------------------------------
// x fp32 -> bf16
// ---------------------------------------------------------------------------
__global__ void convert_x(const float* __restrict__ x, ushort* __restrict__ xb) {
    int i = (blockIdx.x * 256 + threadIdx.x) * 4;
    float4 v = *(const float4*)(x + i);
    ushort4 o;
    o.x = f2bf(v.x); o.y = f2bf(v.y); o.z = f2bf(v.z); o.w = f2bf(v.w);
    *(ushort4*)(xb + i) = o;
}

// ---------------------------------------------------------------------------
// Transpose-convert: src [K][N] fp32 -> dst [N][K] bf16
// ---------------------------------------------------------------------------
__global__ void tconv(const float* __restrict__ src, ushort* __restrict__ dst,
                      int K, int N) {
    __shared__ float T[64][65];
    const int n0 = blockIdx.x * 64, k0 = blockIdx.y * 64;
    const int tid = threadIdx.x;
    #pragma unroll
    for (int s = 0; s < 16; ++s) {
        int idx = tid + s * 256; int r = idx >> 6, cc = idx & 63;
        T[r][cc] = src[(size_t)(k0 + r) * N + n0 + cc];
    }
    __syncthreads();
    #pragma unroll
    for (int s = 0; s < 16; ++s) {
        int idx = tid + s * 256; int r = idx >> 6, cc = idx & 63;
        dst[(size_t)(n0 + r) * K + k0 + cc] = f2bf(T[cc][r]);
    }
}

// ---------------------------------------------------------------------------
// bf16 MFMA GEMM, 64x64 tile, BK=64 (halved barrier count vs R5),
// global_load_lds(16) staging. C[M][N] = A[M][K] @ Bt[N][K]^T.
// ---------------------------------------------------------------------------
template <bool F32OUT>
__global__ __launch_bounds__(256) void gemm64(const ushort* __restrict__ A,
                                              const ushort* __restrict__ Bt,
                                              void* __restrict__ Cv,
                                              int M, int N, int K) {
    __shared__ __align__(16) ushort As[64 * 64];   // 128 B rows
    __shared__ __align__(16) ushort Bs[64 * 64];

    const int tid = threadIdx.x, wave = tid >> 6, lane = tid & 63;
    const int g = lane >> 4, c = lane & 15;
    const int wr = wave >> 1, wc = wave & 1;
    const int m0 = blockIdx.y * 64, n0 = blockIdx.x * 64;

    // staging: DMA instr t covers rows wave*16 + t*8 + (lane>>3), cols (lane&7)*8
    const int srow = lane >> 3, schunk = (lane & 7) * 8;
    const ushort* pa = A  + (size_t)(m0 + wave * 16 + srow) * K + schunk;
    const ushort* pb = Bt + (size_t)(n0 + wave * 16 + srow) * K + schunk;

    float4v acc[2][2] = {{{0,0,0,0},{0,0,0,0}},{{0,0,0,0},{0,0,0,0}}};

    for (int k0 = 0; k0 < K; k0 += 64) {
        #pragma unroll
        for (int t = 0; t < 2; ++t) {
            __builtin_amdgcn_global_load_lds(
                (const __attribute__((address_space(1))) void*)(pa + (size_t)t * 8 * K + k0),
                (__attribute__((address_space(3))) void*)&As[(wave * 16 + t * 8) * 64], 16, 0, 0);
            __builtin_amdgcn_global_load_lds(
                (const __attribute__((address_space(1))) void*)(pb + (size_t)t * 8 * K + k0),
                (__attribute__((address_space(3))) void*)&Bs[(wave * 16 + t * 8) * 64], 16, 0, 0);
        }
        __syncthreads();

        #pragma unroll
        for (int kk = 0; kk < 2; ++kk) {
            short8 af0 = *(const short8*)&As[(wr * 32 + c) * 64 + kk * 32 + 8 * g];
            short8 af1 = *(const short8*)&As[(wr * 32 + 16 + c) * 64 + kk * 32 + 8 * g];
            short8 bf0 = *(const short8*)&Bs[(wc * 32 + c) * 64 + kk * 32 + 8 * g];
            short8 bf1 = *(const short8*)&Bs[(wc * 32 + 16 + c) * 64 + kk * 32 + 8 * g];
            acc[0][0] = __builtin_amdgcn_mfma_f32_16x16x32_bf16(af0, bf0, acc[0][0], 0, 0, 0);
            acc[0][1] = __builtin_amdgcn_mfma_f32_16x16x32_bf16(af0, bf1, acc[0][1], 0, 0, 0);
            acc[1][0] = __builtin_amdgcn_mfma_f32_16x16x32_bf16(af1, bf0, acc[1][0], 0, 0, 0);
            acc[1][1] = __builtin_amdgcn_mfma_f32_16x16x32_bf16(af1, bf1, acc[1][1], 0, 0, 0);
        }
        __syncthreads();
    }

    #pragma unroll
    for (int a = 0; a < 2; ++a)
        #pragma unroll
        for (int bb = 0; bb < 2; ++bb)
            #pragma unroll
            for (int r = 0; r < 4; ++r) {
                int rowi = m0 + wr * 32 + a * 16 + 4 * g + r;
                int coli = n0 + wc * 32 + bb * 16 + c;
                if (F32OUT) ((float*)Cv)[(size_t)rowi * N + coli] = acc[a][bb][r];
                else ((ushort*)Cv)[(size_t)rowi * N + coli] = f2bf(acc[a][bb][r]);
            }
}

// ---------------------------------------------------------------------------
// qkvb [M][1536] bf16 -> Kt[b][j][d] (rope(sum_g k_g)), VtT[b][d][j] (sum_g v).
// PLAIN key order (S^T/PV-direct scheme needs no permutation).
// ---------------------------------------------------------------------------
__global__ void kv_reduce2(const ushort* __restrict__ qkvb,
                           ushort* __restrict__ Kt, ushort* __restrict__ VtT) {
    const int wid = threadIdx.x >> 6, d = threadIdx.x & 63;
    const int rowg = blockIdx.x * 4 + wid;          // b*N + n
    const int n = rowg & (N_ - 1), b = rowg >> 11;

    const ushort* base = qkvb + (size_t)rowg * 1536 + 1024;
    float ks = 0.f, vs = 0.f;
    #pragma unroll
    for (int g = 0; g < G_; ++g) {
        ks += bf2f(base[g * 64 + d]);
        vs += bf2f(base[256 + g * 64 + d]);
    }
    float partner = __shfl_xor(ks, 32, 64);
    float rh = (d < 32) ? -partner : partner;
    float ang = (float)n * __powf(10000.0f, -(float)(d & 31) * (1.0f / 32.0f));
    float sn, cs; __sincosf(ang, &sn, &cs);

    Kt[(size_t)rowg * 64 + d] = f2bf(ks * cs + rh * sn);
    VtT[((size_t)b * 64 + d) * N_ + n] = f2bf(vs);
}

// ---------------------------------------------------------------------------
// Flash attention v7: S^T scheme. mfma(kf,qf) -> S^T in C-layout, whose
// registers ARE the 16x16x16 B-fragment (k=4g+i) after bf16 packing: PV runs
// as O^T = mfma16(V^T-frag, P^T) with ZERO LDS ops for P. 4 waves x 64 rows,
// K-split x2, register staging + 2 barriers (attn3-proven), XOR swizzle.
// l via per-lane adds + 2 end shuffles.
// ---------------------------------------------------------------------------
#define QSCALE 0.18033688011112042f   // 0.125 * log2(e)

__global__ __launch_bounds__(256) void attn7(
        const ushort* __restrict__ qkvb, const ushort* __restrict__ Kt,
        const ushort* __restrict__ VtT,
        ushort* __restrict__ oP0, ushort* __restrict__ oP1,
        float* __restrict__ lP0, float* __restrict__ lP1) {
    const int s  = blockIdx.x & 1;
    const int qt = (blockIdx.x >> 1) & 7;
    const int h  = (blockIdx.x >> 4) & 15;
    const int b  = blockIdx.x >> 8;
    const int tid = threadIdx.x, wave = tid >> 6, lane = tid & 63;
    const int g = lane >> 4, c = lane & 15;

    __shared__ __align__(16) ushort Ksh[64 * 64];   // [j-local][d], 128 B rows, swizzled
    __shared__ __align__(16) ushort Vsh[64 * 64];   // [d][j-local], swizzled

    ushort* oPs = s ? oP1 : oP0;
    float*  lPs = s ? lP1 : lP0;

    const int i0 = qt * 256 + wave * 64;
    // Q prologue: RoPE + scale (d<->d+32 partner = register pair)
    short8 qf[4][2];
    #pragma unroll
    for (int a = 0; a < 4; ++a) {
        const int row = i0 + a * 16 + c;
        const ushort* qrow = qkvb + (size_t)(b * N_ + row) * 1536 + h * 64;
        short8 raw0 = *(const short8*)(qrow + 8 * g);
        short8 raw1 = *(const short8*)(qrow + 32 + 8 * g);
        #pragma unroll
        for (int i = 0; i < 8; ++i) {
            int dd = 8 * g + i;
            float f0 = bf2f((ushort)raw0[i]), f1 = bf2f((ushort)raw1[i]);
            float ang = (float)row * __powf(10000.0f, -(float)dd * (1.0f / 32.0f));
            float sn, cs; __sincosf(ang, &sn, &cs);
            qf[a][0][i] = (short)f2bf((f0 * cs - f1 * sn) * QSCALE);
            qf[a][1][i] = (short)f2bf((f1 * cs + f0 * sn) * QSCALE);
        }
    }

    float4v o[4][4];           // O^T accumulators: [a: i-tile][f: d-tile]
    #pragma unroll
    for (int a = 0; a < 4; ++a)
        #pragma unroll
        for (int f = 0; f < 4; ++f) o[a][f] = {0, 0, 0, 0};
    float ll[4] = {0.f, 0.f, 0.f, 0.f};

    const ushort* Kb = Kt  + (size_t)b * N_ * 64;
    const ushort* Vb = VtT + (size_t)b * 64 * N_;
    const int lr8 = lane >> 3, lq8 = lane & 7;
    const int wpos = (lq8 ^ lr8) * 8;                // swizzled chunk position (elems)
    const int j0 = s * (N_ / 2);
    const int NT = (N_ / 2) / 64;                    // 16 tiles

    // register staging (attn3-proven): 2 K + 2 V short8 per wave
    short8 kr0 = *(const short8*)(Kb + (size_t)(j0 + wave * 16 + lr8) * 64 + lq8 * 8);
    short8 kr1 = *(const short8*)(Kb + (size_t)(j0 + wave * 16 + 8 + lr8) * 64 + lq8 * 8);
    short8 vr0 = *(const short8*)(Vb + (size_t)(wave * 16 + lr8) * N_ + j0 + lq8 * 8);
    short8 vr1 = *(const short8*)(Vb + (size_t)(wave * 16 + 8 + lr8) * N_ + j0 + lq8 * 8);

    for (int t = 0; t < NT; ++t) {
        __syncthreads();   // prev-tile LDS reads complete
        *(short8*)&Ksh[(wave * 16 + lr8) * 64 + wpos]     = kr0;
        *(short8*)&Ksh[(wave * 16 + 8 + lr8) * 64 + wpos] = kr1;
        *(short8*)&Vsh[(wave * 16 + lr8) * 64 + wpos]     = vr0;
        *(short8*)&Vsh[(wave * 16 + 8 + lr8) * 64 + wpos] = vr1;
        __syncthreads();   // tile ready
        if (t + 1 < NT) {
            const int jn = j0 + (t + 1) * 64;
            kr0 = *(const short8*)(Kb + (size_t)(jn + wave * 16 + lr8) * 64 + lq8 * 8);
            kr1 = *(const short8*)(Kb + (size_t)(jn + wave * 16 + 8 + lr8) * 64 + lq8 * 8);
            vr0 = *(const short8*)(Vb + (size_t)(wave * 16 + lr8) * N_ + jn + lq8 * 8);
            vr1 = *(const short8*)(Vb + (size_t)(wave * 16 + 8 + lr8) * N_ + jn + lq8 * 8);
        }

        #pragma unroll
        for (int jt4 = 0; jt4 < 4; ++jt4) {
            // K fragments (shared across all 4 row-groups): A-frag rows j-local
            const int R = jt4 * 16 + c;
            short8 kf0 = *(const short8*)&Ksh[R * 64 + ((g ^ (c & 7)) * 8)];
            short8 kf1 = *(const short8*)&Ksh[R * 64 + (((g ^ 4) ^ (c & 7)) * 8)];
            // V fragments (b64, shared across row-groups): A[m=d-local][k=4g+i]
            short4v vf[4];
            #pragma unroll
            for (int f = 0; f < 4; ++f)
                vf[f] = *(const short4v*)&Vsh[(16 * f + c) * 64 +
                          (((jt4 * 2 + (g >> 1)) ^ (c & 7)) * 8) + (g & 1) * 4];

            #pragma unroll
            for (int a = 0; a < 4; ++a) {
                float4v st = {0, 0, 0, 0};   // S^T tile: rows j=4g+r, col i=c
                st = __builtin_amdgcn_mfma_f32_16x16x32_bf16(kf0, qf[a][0], st, 0, 0, 0);
                st = __builtin_amdgcn_mfma_f32_16x16x32_bf16(kf1, qf[a][1], st, 0, 0, 0);
                float p0 = fexp2(st[0]), p1 = fexp2(st[1]);
                float p2 = fexp2(st[2]), p3 = fexp2(st[3]);
                ll[a] += (p0 + p1) + (p2 + p3);
                union { unsigned u[2]; short4v v; } pk;
                pk.u[0] = pack_bf16(p0, p1);
                pk.u[1] = pack_bf16(p2, p3);
                #pragma unroll
                for (int f = 0; f < 4; ++f)
                    o[a][f] = MFMA16K16(vf[f], pk.v, o[a][f]);
            }
        }
    }

    // epilogue: O^T C-layout -> row-packed ushort4 stores; l reduce across g
    #pragma unroll
    for (int a = 0; a < 4; ++a) {
        float lt = ll[a];
        lt += __shfl_xor(lt, 16, 64);
        lt += __shfl_xor(lt, 32, 64);
        const int row = i0 + a * 16 + c;
        if (g == 0) lPs[(size_t)(b * N_ + row) * 16 + h] = lt;
        #pragma unroll
        for (int f = 0; f < 4; ++f) {
            ushort4 w;
            w.x = f2bf(o[a][f][0]); w.y = f2bf(o[a][f][1]);
            w.z = f2bf(o[a][f][2]); w.w = f2bf(o[a][f][3]);
            *(ushort4*)(oPs + (size_t)(b * N_ + row) * 1024 + h * 64 + 16 * f + 4 * g) = w;
        }
    }
}

// ---------------------------------------------------------------------------
// Combine: ao = (oP0 + oP1) / (lP0 + lP1), bf16 out (in-place over oP0 ok)
// ---------------------------------------------------------------------------
__global__ void combine(const ushort* __restrict__ oP0, const ushort* __restrict__ oP1,
                        const float* __restrict__ lP0, const float* __restrict__ lP1,
                        ushort* __restrict__ ao) {
    const int e = (blockIdx.x * 256 + threadIdx.x) * 4;
    const int row = e >> 10, hh = (e >> 6) & 15;
    const float inv = 1.0f / (lP0[row * 16 + hh] + lP1[row * 16 + hh]);
    ushort4 a = *(const ushort4*)(oP0 + e);
    ushort4 b = *(const ushort4*)(oP1 + e);
    ushort4 r;
    r.x = f2bf((bf2f(a.x) + bf2f(b.x)) * inv);
    r.y = f2bf((bf2f(a.y) + bf2f(b.y)) * inv);
    r.z = f2bf((bf2f(a.z) + bf2f(b.z)) * inv);
    r.w = f2bf((bf2f(a.w) + bf2f(b.w)) * inv);
    *(ushort4*)(ao + e) = r;
}

// ---------------------------------------------------------------------------
extern "C" void kernel_launch(void* const* d_in, const int* in_sizes, int n_in,
                              void* d_out, int out_size, void* d_ws, size_t ws_size,
                              hipStream_t stream) {
    const float* x     = (const float*)d_in[0];
    const float* w_q   = (const float*)d_in[1];
    const float* w_kv  = (const float*)d_in[2];
    const float* w_out = (const float*)d_in[3];
    float* out = (float*)d_out;

    const int M = B_ * N_;                               // 4096
    ushort* xb    = (ushort*)d_ws;                       // 4096*1024  (-> oP0 -> ao)
    ushort* wqkvT = xb    + (size_t)M * C_;              // 1536*1024
    ushort* woutT = wqkvT + (size_t)1536 * C_;           // 1024*1024
    ushort* qkvb  = woutT + (size_t)C_ * C_;             // 4096*1536
    ushort* Kt    = qkvb  + (size_t)M * 1536;            // 2*2048*64
    ushort* VtT   = Kt    + (size_t)B_ * N_ * D_;        // 2*64*2048
    ushort* oP1   = VtT   + (size_t)B_ * D_ * N_;        // 4096*1024 bf16 partial
    float*  lP0   = (float*)(oP1 + (size_t)M * C_);      // 4096*16 fp32
    float*  lP1   = lP0 + (size_t)M * H_;
    ushort* oP0   = xb;   // xb dead after qkv GEMM
    ushort* ao    = xb;   // combine writes in-place over oP0

    convert_x<<<(M * C_) / 1024, 256, 0, stream>>>(x, xb);
    tconv<<<dim3(16, 16), 256, 0, stream>>>(w_q,  wqkvT,                   C_, C_);
    tconv<<<dim3(8, 16),  256, 0, stream>>>(w_kv, wqkvT + (size_t)C_ * C_, C_, 2 * G_ * D_);
    tconv<<<dim3(16, 16), 256, 0, stream>>>(w_out, woutT,                  C_, C_);

    gemm64<false><<<dim3(1536 / 64, M / 64), 256, 0, stream>>>(xb, wqkvT, qkvb, M, 1536, C_);
    kv_reduce2<<<M / 4, 256, 0, stream>>>(qkvb, Kt, VtT);
    attn7<<<B_ * H_ * (N_ / 256) * 2, 256, 0, stream>>>(qkvb, Kt, VtT, oP0, oP1, lP0, lP1);
    combine<<<(M * C_) / 1024, 256, 0, stream>>>(oP0, oP1, lP0, lP1, ao);
    gemm64<true><<<dim3(C_ / 64, M / 64), 256, 0, stream>>>(ao, woutT, out, M, C_, C_);
}

// Round 8
// 189.881 us; speedup vs baseline: 1.1920x; 1.0363x over previous
//
#include <hip/hip_runtime.h>
#include <hip/hip_bf16.h>
#include <math.h>

#define B_ 2
#define N_ 2048
#define C_ 1024
#define H_ 16
#define G_ 4
#define D_ 64

using short8  = __attribute__((ext_vector_type(8))) short;
using short4v = __attribute__((ext_vector_type(4))) short;
using float4v = __attribute__((ext_vector_type(4))) float;

#if __has_builtin(__builtin_amdgcn_mfma_f32_16x16x16_bf16)
#define MFMA16K16(A, B, C) __builtin_amdgcn_mfma_f32_16x16x16_bf16(A, B, C, 0, 0, 0)
#else
#define MFMA16K16(A, B, C) __builtin_amdgcn_mfma_f32_16x16x16bf16_1k(A, B, C, 0, 0, 0)
#endif

__device__ __forceinline__ ushort f2bf(float f) {
    union { float f; unsigned u; } v; v.f = f;
    unsigned r = (v.u + 0x7FFF + ((v.u >> 16) & 1)) >> 16;  // RNE
    return (ushort)r;
}
__device__ __forceinline__ float bf2f(ushort u) {
    union { unsigned u; float f; } t; t.u = ((unsigned)u) << 16; return t.f;
}
__device__ __forceinline__ unsigned pack_bf16(float a, float b) {
#if __has_builtin(__builtin_amdgcn_cvt_pk_bf16_f32)
    auto t = __builtin_amdgcn_cvt_pk_bf16_f32(a, b);
    unsigned r; __builtin_memcpy(&r, &t, 4); return r;
#else
    return (unsigned)f2bf(a) | ((unsigned)f2bf(b) << 16);
#endif
}
__device__ __forceinline__ float fexp2(float x) {
#if __has_builtin(__builtin_amdgcn_exp2f)
    return __builtin_amdgcn_exp2f(x);
#else
    return exp2f(x);
#endif
}

// ---------------------------------------------------------------------------
// x fp32 -> bf16
// ---------------------------------------------------------------------------
__global__ void convert_x(const float* __restrict__ x, ushort* __restrict__ xb) {
    int i = (blockIdx.x * 256 + threadIdx.x) * 4;
    float4 v = *(const float4*)(x + i);
    ushort4 o;
    o.x = f2bf(v.x); o.y = f2bf(v.y); o.z = f2bf(v.z); o.w = f2bf(v.w);
    *(ushort4*)(xb + i) = o;
}

// ---------------------------------------------------------------------------
// Transpose-convert: src [K][N] fp32 -> dst [N][K] bf16
// ---------------------------------------------------------------------------
__global__ void tconv(const float* __restrict__ src, ushort* __restrict__ dst,
                      int K, int N) {
    __shared__ float T[64][65];
    const int n0 = blockIdx.x * 64, k0 = blockIdx.y * 64;
    const int tid = threadIdx.x;
    #pragma unroll
    for (int s = 0; s < 16; ++s) {
        int idx = tid + s * 256; int r = idx >> 6, cc = idx & 63;
        T[r][cc] = src[(size_t)(k0 + r) * N + n0 + cc];
    }
    __syncthreads();
    #pragma unroll
    for (int s = 0; s < 16; ++s) {
        int idx = tid + s * 256; int r = idx >> 6, cc = idx & 63;
        dst[(size_t)(n0 + r) * K + k0 + cc] = f2bf(T[cc][r]);
    }
}

// ---------------------------------------------------------------------------
// bf16 MFMA GEMM, 64x64 tile, BK=64, global_load_lds(16) staging with
// GLOBAL-SIDE XOR chunk swizzle: LDS position p holds global chunk p^(row&7),
// so fragment reads (chunk w at position w^(c&7)) are loop-invariant AND
// 2-way banked (fixes the 16-way conflict of the plain 128 B row stride).
// C[M][N] = A[M][K] @ Bt[N][K]^T.
// ---------------------------------------------------------------------------
template <bool F32OUT>
__global__ __launch_bounds__(256) void gemm64(const ushort* __restrict__ A,
                                              const ushort* __restrict__ Bt,
                                              void* __restrict__ Cv,
                                              int M, int N, int K) {
    __shared__ __align__(16) ushort As[64 * 64];   // 128 B rows, swizzled chunks
    __shared__ __align__(16) ushort Bs[64 * 64];

    const int tid = threadIdx.x, wave = tid >> 6, lane = tid & 63;
    const int g = lane >> 4, c = lane & 15;
    const int wr = wave >> 1, wc = wave & 1;
    const int m0 = blockIdx.y * 64, n0 = blockIdx.x * 64;

    // staging: DMA instr t covers rows wave*16 + t*8 + lr8; global chunk XOR'd
    const int lr8 = lane >> 3, lq8 = lane & 7;
    const int gchunk = (lq8 ^ lr8) * 8;            // global source chunk (swizzle)
    const ushort* pa = A  + (size_t)(m0 + wave * 16 + lr8) * K + gchunk;
    const ushort* pb = Bt + (size_t)(n0 + wave * 16 + lr8) * K + gchunk;

    float4v acc[2][2] = {{{0,0,0,0},{0,0,0,0}},{{0,0,0,0},{0,0,0,0}}};

    for (int k0 = 0; k0 < K; k0 += 64) {
        #pragma unroll
        for (int t = 0; t < 2; ++t) {
            __builtin_amdgcn_global_load_lds(
                (const __attribute__((address_space(1))) void*)(pa + (size_t)t * 8 * K + k0),
                (__attribute__((address_space(3))) void*)&As[(wave * 16 + t * 8) * 64], 16, 0, 0);
            __builtin_amdgcn_global_load_lds(
                (const __attribute__((address_space(1))) void*)(pb + (size_t)t * 8 * K + k0),
                (__attribute__((address_space(3))) void*)&Bs[(wave * 16 + t * 8) * 64], 16, 0, 0);
        }
        __syncthreads();

        #pragma unroll
        for (int kk = 0; kk < 2; ++kk) {
            const int c7 = c & 7;
            short8 af0 = *(const short8*)&As[(wr * 32 + c) * 64 + ((kk * 4 + g) ^ c7) * 8];
            short8 af1 = *(const short8*)&As[(wr * 32 + 16 + c) * 64 + ((kk * 4 + g) ^ c7) * 8];
            short8 bf0 = *(const short8*)&Bs[(wc * 32 + c) * 64 + ((kk * 4 + g) ^ c7) * 8];
            short8 bf1 = *(const short8*)&Bs[(wc * 32 + 16 + c) * 64 + ((kk * 4 + g) ^ c7) * 8];
            acc[0][0] = __builtin_amdgcn_mfma_f32_16x16x32_bf16(af0, bf0, acc[0][0], 0, 0, 0);
            acc[0][1] = __builtin_amdgcn_mfma_f32_16x16x32_bf16(af0, bf1, acc[0][1], 0, 0, 0);
            acc[1][0] = __builtin_amdgcn_mfma_f32_16x16x32_bf16(af1, bf0, acc[1][0], 0, 0, 0);
            acc[1][1] = __builtin_amdgcn_mfma_f32_16x16x32_bf16(af1, bf1, acc[1][1], 0, 0, 0);
        }
        __syncthreads();
    }

    #pragma unroll
    for (int a = 0; a < 2; ++a)
        #pragma unroll
        for (int bb = 0; bb < 2; ++bb)
            #pragma unroll
            for (int r = 0; r < 4; ++r) {
                int rowi = m0 + wr * 32 + a * 16 + 4 * g + r;
                int coli = n0 + wc * 32 + bb * 16 + c;
                if (F32OUT) ((float*)Cv)[(size_t)rowi * N + coli] = acc[a][bb][r];
                else ((ushort*)Cv)[(size_t)rowi * N + coli] = f2bf(acc[a][bb][r]);
            }
}

// ---------------------------------------------------------------------------
// qkvb [M][1536] bf16 -> Kt[b][j][d] (rope(sum_g k_g)), VtT[b][d][j] (sum_g v).
// ---------------------------------------------------------------------------
__global__ void kv_reduce2(const ushort* __restrict__ qkvb,
                           ushort* __restrict__ Kt, ushort* __restrict__ VtT) {
    const int wid = threadIdx.x >> 6, d = threadIdx.x & 63;
    const int rowg = blockIdx.x * 4 + wid;          // b*N + n
    const int n = rowg & (N_ - 1), b = rowg >> 11;

    const ushort* base = qkvb + (size_t)rowg * 1536 + 1024;
    float ks = 0.f, vs = 0.f;
    #pragma unroll
    for (int g = 0; g < G_; ++g) {
        ks += bf2f(base[g * 64 + d]);
        vs += bf2f(base[256 + g * 64 + d]);
    }
    float partner = __shfl_xor(ks, 32, 64);
    float rh = (d < 32) ? -partner : partner;
    float ang = (float)n * __powf(10000.0f, -(float)(d & 31) * (1.0f / 32.0f));
    float sn, cs; __sincosf(ang, &sn, &cs);

    Kt[(size_t)rowg * 64 + d] = f2bf(ks * cs + rh * sn);
    VtT[((size_t)b * 64 + d) * N_ + n] = f2bf(vs);
}

// ---------------------------------------------------------------------------
// Flash attention v8: S^T scheme (PV via 16x16x16, zero LDS for P) with
// PLAIN padded LDS (stride 72 elems = 144 B): every ds_read offset is
// base + compile-time immediate (no per-iter address VALU), all accesses
// ~2-way banked. 4 waves x 64 rows, K-split x2, register staging.
// ---------------------------------------------------------------------------
#define KSV 72                        // padded row stride (elems)
#define QSCALE 0.18033688011112042f   // 0.125 * log2(e)

__global__ __launch_bounds__(256) void attn8(
        const ushort* __restrict__ qkvb, const ushort* __restrict__ Kt,
        const ushort* __restrict__ VtT,
        ushort* __restrict__ oP0, ushort* __restrict__ oP1,
        float* __restrict__ lP0, float* __restrict__ lP1) {
    const int s  = blockIdx.x & 1;
    const int qt = (blockIdx.x >> 1) & 7;
    const int h  = (blockIdx.x >> 4) & 15;
    const int b  = blockIdx.x >> 8;
    const int tid = threadIdx.x, wave = tid >> 6, lane = tid & 63;
    const int g = lane >> 4, c = lane & 15;

    __shared__ __align__(16) ushort Ksh[64 * KSV];  // [j-local][d], plain chunks
    __shared__ __align__(16) ushort Vsh[64 * KSV];  // [d][j-local], plain chunks

    ushort* oPs = s ? oP1 : oP0;
    float*  lPs = s ? lP1 : lP0;

    const int i0 = qt * 256 + wave * 64;
    // Q prologue: RoPE + scale; inv-freqs hoisted (dd = 8g+i fixed per lane)
    float invf[8];
    #pragma unroll
    for (int i = 0; i < 8; ++i)
        invf[i] = __powf(10000.0f, -(float)(8 * g + i) * (1.0f / 32.0f));

    short8 qf[4][2];
    #pragma unroll
    for (int a = 0; a < 4; ++a) {
        const int row = i0 + a * 16 + c;
        const ushort* qrow = qkvb + (size_t)(b * N_ + row) * 1536 + h * 64;
        short8 raw0 = *(const short8*)(qrow + 8 * g);
        short8 raw1 = *(const short8*)(qrow + 32 + 8 * g);
        #pragma unroll
        for (int i = 0; i < 8; ++i) {
            float f0 = bf2f((ushort)raw0[i]), f1 = bf2f((ushort)raw1[i]);
            float sn, cs; __sincosf((float)row * invf[i], &sn, &cs);
            qf[a][0][i] = (short)f2bf((f0 * cs - f1 * sn) * QSCALE);
            qf[a][1][i] = (short)f2bf((f1 * cs + f0 * sn) * QSCALE);
        }
    }

    float4v o[4][4];           // O^T accumulators: [a: i-tile][f: d-tile]
    #pragma unroll
    for (int a = 0; a < 4; ++a)
        #pragma unroll
        for (int f = 0; f < 4; ++f) o[a][f] = {0, 0, 0, 0};
    float ll[4] = {0.f, 0.f, 0.f, 0.f};

    const ushort* Kb = Kt  + (size_t)b * N_ * 64;
    const ushort* Vb = VtT + (size_t)b * 64 * N_;
    const int lr8 = lane >> 3, lq8 = lane & 7;
    const int j0 = s * (N_ / 2);
    const int NT = (N_ / 2) / 64;                    // 16 tiles

    // register staging: 2 K + 2 V short8 per wave
    short8 kr0 = *(const short8*)(Kb + (size_t)(j0 + wave * 16 + lr8) * 64 + lq8 * 8);
    short8 kr1 = *(const short8*)(Kb + (size_t)(j0 + wave * 16 + 8 + lr8) * 64 + lq8 * 8);
    short8 vr0 = *(const short8*)(Vb + (size_t)(wave * 16 + lr8) * N_ + j0 + lq8 * 8);
    short8 vr1 = *(const short8*)(Vb + (size_t)(wave * 16 + 8 + lr8) * N_ + j0 + lq8 * 8);

    for (int t = 0; t < NT; ++t) {
        __syncthreads();   // prev-tile LDS reads complete
        *(short8*)&Ksh[(wave * 16 + lr8) * KSV + lq8 * 8]     = kr0;
        *(short8*)&Ksh[(wave * 16 + 8 + lr8) * KSV + lq8 * 8] = kr1;
        *(short8*)&Vsh[(wave * 16 + lr8) * KSV + lq8 * 8]     = vr0;
        *(short8*)&Vsh[(wave * 16 + 8 + lr8) * KSV + lq8 * 8] = vr1;
        __syncthreads();   // tile ready
        if (t + 1 < NT) {
            const int jn = j0 + (t + 1) * 64;
            kr0 = *(const short8*)(Kb + (size_t)(jn + wave * 16 + lr8) * 64 + lq8 * 8);
            kr1 = *(const short8*)(Kb + (size_t)(jn + wave * 16 + 8 + lr8) * 64 + lq8 * 8);
            vr0 = *(const short8*)(Vb + (size_t)(wave * 16 + lr8) * N_ + jn + lq8 * 8);
            vr1 = *(const short8*)(Vb + (size_t)(wave * 16 + 8 + lr8) * N_ + jn + lq8 * 8);
        }

        #pragma unroll
        for (int jt4 = 0; jt4 < 4; ++jt4) {
            // K fragments (A-frag rows = j-local): plain offsets, affine in jt4
            const int R = jt4 * 16 + c;
            short8 kf0 = *(const short8*)&Ksh[R * KSV + 8 * g];
            short8 kf1 = *(const short8*)&Ksh[R * KSV + 32 + 8 * g];
            // V fragments (A[m=d-local][k=4g+i]): b64, affine in jt4 and f
            short4v vf[4];
            #pragma unroll
            for (int f = 0; f < 4; ++f)
                vf[f] = *(const short4v*)&Vsh[(16 * f + c) * KSV + jt4 * 16 + 4 * g];

            #pragma unroll
            for (int a = 0; a < 4; ++a) {
                float4v st = {0, 0, 0, 0};   // S^T tile: rows j=4g+r, col i=c
                st = __builtin_amdgcn_mfma_f32_16x16x32_bf16(kf0, qf[a][0], st, 0, 0, 0);
                st = __builtin_amdgcn_mfma_f32_16x16x32_bf16(kf1, qf[a][1], st, 0, 0, 0);
                float p0 = fexp2(st[0]), p1 = fexp2(st[1]);
                float p2 = fexp2(st[2]), p3 = fexp2(st[3]);
                ll[a] += (p0 + p1) + (p2 + p3);
                union { unsigned u[2]; short4v v; } pk;
                pk.u[0] = pack_bf16(p0, p1);
                pk.u[1] = pack_bf16(p2, p3);
                #pragma unroll
                for (int f = 0; f < 4; ++f)
                    o[a][f] = MFMA16K16(vf[f], pk.v, o[a][f]);
            }
        }
    }

    // epilogue: O^T C-layout -> row-packed ushort4 stores; l reduce across g
    #pragma unroll
    for (int a = 0; a < 4; ++a) {
        float lt = ll[a];
        lt += __shfl_xor(lt, 16, 64);
        lt += __shfl_xor(lt, 32, 64);
        const int row = i0 + a * 16 + c;
        if (g == 0) lPs[(size_t)(b * N_ + row) * 16 + h] = lt;
        #pragma unroll
        for (int f = 0; f < 4; ++f) {
            ushort4 w;
            w.x = f2bf(o[a][f][0]); w.y = f2bf(o[a][f][1]);
            w.z = f2bf(o[a][f][2]); w.w = f2bf(o[a][f][3]);
            *(ushort4*)(oPs + (size_t)(b * N_ + row) * 1024 + h * 64 + 16 * f + 4 * g) = w;
        }
    }
}

// ---------------------------------------------------------------------------
// Combine: ao = (oP0 + oP1) / (lP0 + lP1), bf16 out (in-place over oP0 ok)
// ---------------------------------------------------------------------------
__global__ void combine(const ushort* __restrict__ oP0, const ushort* __restrict__ oP1,
                        const float* __restrict__ lP0, const float* __restrict__ lP1,
                        ushort* __restrict__ ao) {
    const int e = (blockIdx.x * 256 + threadIdx.x) * 4;
    const int row = e >> 10, hh = (e >> 6) & 15;
    const float inv = 1.0f / (lP0[row * 16 + hh] + lP1[row * 16 + hh]);
    ushort4 a = *(const ushort4*)(oP0 + e);
    ushort4 b = *(const ushort4*)(oP1 + e);
    ushort4 r;
    r.x = f2bf((bf2f(a.x) + bf2f(b.x)) * inv);
    r.y = f2bf((bf2f(a.y) + bf2f(b.y)) * inv);
    r.z = f2bf((bf2f(a.z) + bf2f(b.z)) * inv);
    r.w = f2bf((bf2f(a.w) + bf2f(b.w)) * inv);
    *(ushort4*)(ao + e) = r;
}

// ---------------------------------------------------------------------------
extern "C" void kernel_launch(void* const* d_in, const int* in_sizes, int n_in,
                              void* d_out, int out_size, void* d_ws, size_t ws_size,
                              hipStream_t stream) {
    const float* x     = (const float*)d_in[0];
    const float* w_q   = (const float*)d_in[1];
    const float* w_kv  = (const float*)d_in[2];
    const float* w_out = (const float*)d_in[3];
    float* out = (float*)d_out;

    const int M = B_ * N_;                               // 4096
    ushort* xb    = (ushort*)d_ws;                       // 4096*1024  (-> oP0 -> ao)
    ushort* wqkvT = xb    + (size_t)M * C_;              // 1536*1024
    ushort* woutT = wqkvT + (size_t)1536 * C_;           // 1024*1024
    ushort* qkvb  = woutT + (size_t)C_ * C_;             // 4096*1536
    ushort* Kt    = qkvb  + (size_t)M * 1536;            // 2*2048*64
    ushort* VtT   = Kt    + (size_t)B_ * N_ * D_;        // 2*64*2048
    ushort* oP1   = VtT   + (size_t)B_ * D_ * N_;        // 4096*1024 bf16 partial
    float*  lP0   = (float*)(oP1 + (size_t)M * C_);      // 4096*16 fp32
    float*  lP1   = lP0 + (size_t)M * H_;
    ushort* oP0   = xb;   // xb dead after qkv GEMM
    ushort* ao    = xb;   // combine writes in-place over oP0

    convert_x<<<(M * C_) / 1024, 256, 0, stream>>>(x, xb);
    tconv<<<dim3(16, 16), 256, 0, stream>>>(w_q,  wqkvT,                   C_, C_);
    tconv<<<dim3(8, 16),  256, 0, stream>>>(w_kv, wqkvT + (size_t)C_ * C_, C_, 2 * G_ * D_);
    tconv<<<dim3(16, 16), 256, 0, stream>>>(w_out, woutT,                  C_, C_);

    gemm64<false><<<dim3(1536 / 64, M / 64), 256, 0, stream>>>(xb, wqkvT, qkvb, M, 1536, C_);
    kv_reduce2<<<M / 4, 256, 0, stream>>>(qkvb, Kt, VtT);
    attn8<<<B_ * H_ * (N_ / 256) * 2, 256, 0, stream>>>(qkvb, Kt, VtT, oP0, oP1, lP0, lP1);
    combine<<<(M * C_) / 1024, 256, 0, stream>>>(oP0, oP1, lP0, lP1, ao);
    gemm64<true><<<dim3(C_ / 64, M / 64), 256, 0, stream>>>(ao, woutT, out, M, C_, C_);
}

// Round 9
// 182.304 us; speedup vs baseline: 1.2416x; 1.0416x over previous
//
#include <hip/hip_runtime.h>
#include <hip/hip_bf16.h>
#include <math.h>

#define B_ 2
#define N_ 2048
#define C_ 1024
#define H_ 16
#define G_ 4
#define D_ 64
#define QKV_N 1152   // 1024 q + 64 ksum + 64 vsum

using short8  = __attribute__((ext_vector_type(8))) short;
using short4v = __attribute__((ext_vector_type(4))) short;
using float4v = __attribute__((ext_vector_type(4))) float;

#if __has_builtin(__builtin_amdgcn_mfma_f32_16x16x16_bf16)
#define MFMA16K16(A, B, C) __builtin_amdgcn_mfma_f32_16x16x16_bf16(A, B, C, 0, 0, 0)
#else
#define MFMA16K16(A, B, C) __builtin_amdgcn_mfma_f32_16x16x16bf16_1k(A, B, C, 0, 0, 0)
#endif

__device__ __forceinline__ ushort f2bf(float f) {
    union { float f; unsigned u; } v; v.f = f;
    unsigned r = (v.u + 0x7FFF + ((v.u >> 16) & 1)) >> 16;  // RNE
    return (ushort)r;
}
__device__ __forceinline__ float bf2f(ushort u) {
    union { unsigned u; float f; } t; t.u = ((unsigned)u) << 16; return t.f;
}
__device__ __forceinline__ unsigned pack_bf16(float a, float b) {
#if __has_builtin(__builtin_amdgcn_cvt_pk_bf16_f32)
    auto t = __builtin_amdgcn_cvt_pk_bf16_f32(a, b);
    unsigned r; __builtin_memcpy(&r, &t, 4); return r;
#else
    return (unsigned)f2bf(a) | ((unsigned)f2bf(b) << 16);
#endif
}
__device__ __forceinline__ float fexp2(float x) {
#if __has_builtin(__builtin_amdgcn_exp2f)
    return __builtin_amdgcn_exp2f(x);
#else
    return exp2f(x);
#endif
}

// ---------------------------------------------------------------------------
// Fused prep (one launch):
//   blocks [0,4096)     : x fp32 -> bf16
//   [4096,4352)         : w_q^T   -> wqkvT rows 0..1023
//   [4352,4608)         : w_out^T -> woutT
//   [4608,4624)         : kv weight g-sum + transpose -> wqkvT rows 1024..1151
// ---------------------------------------------------------------------------
__device__ void tconv_body(const float* __restrict__ src, ushort* __restrict__ dst,
                           int K, int N, int bx, int by, float (*T)[65]) {
    const int n0 = bx * 64, k0 = by * 64;
    const int tid = threadIdx.x;
    #pragma unroll
    for (int s = 0; s < 16; ++s) {
        int idx = tid + s * 256; int r = idx >> 6, cc = idx & 63;
        T[r][cc] = src[(size_t)(k0 + r) * N + n0 + cc];
    }
    __syncthreads();
    #pragma unroll
    for (int s = 0; s < 16; ++s) {
        int idx = tid + s * 256; int r = idx >> 6, cc = idx & 63;
        dst[(size_t)(n0 + r) * K + k0 + cc] = f2bf(T[cc][r]);
    }
}

__global__ void prep(const float* __restrict__ x, const float* __restrict__ w_q,
                     const float* __restrict__ w_kv, const float* __restrict__ w_out,
                     ushort* __restrict__ xb, ushort* __restrict__ wqkvT,
                     ushort* __restrict__ woutT) {
    __shared__ float T[64][65];
    const int blk = blockIdx.x, tid = threadIdx.x;
    if (blk < 4096) {
        int i = blk * 1024 + tid * 4;
        float4 v = *(const float4*)(x + i);
        ushort4 o;
        o.x = f2bf(v.x); o.y = f2bf(v.y); o.z = f2bf(v.z); o.w = f2bf(v.w);
        *(ushort4*)(xb + i) = o;
    } else if (blk < 4352) {
        int idx = blk - 4096;
        tconv_body(w_q, wqkvT, C_, C_, idx & 15, idx >> 4, T);
    } else if (blk < 4608) {
        int idx = blk - 4352;
        tconv_body(w_out, woutT, C_, C_, idx & 15, idx >> 4, T);
    } else {
        // kv g-sum + transpose: wqkvT[1024+d][k] = sum_g w_kv[k][g*64+d],
        //                       wqkvT[1088+d][k] = sum_g w_kv[k][256+g*64+d]
        const int k0 = (blk - 4608) * 64;
        #pragma unroll
        for (int it = 0; it < 4; ++it) {
            int p = tid + it * 256;              // 1024 (kk, d-quad) pairs
            int kk = p >> 4, d4 = (p & 15) * 4;
            float ks[4] = {0, 0, 0, 0}, vs[4] = {0, 0, 0, 0};
            #pragma unroll
            for (int g = 0; g < G_; ++g) {
                float4 a = *(const float4*)(w_kv + (size_t)(k0 + kk) * 512 + g * 64 + d4);
                float4 b = *(const float4*)(w_kv + (size_t)(k0 + kk) * 512 + 256 + g * 64 + d4);
                ks[0] += a.x; ks[1] += a.y; ks[2] += a.z; ks[3] += a.w;
                vs[0] += b.x; vs[1] += b.y; vs[2] += b.z; vs[3] += b.w;
            }
            #pragma unroll
            for (int e = 0; e < 4; ++e) {
                wqkvT[(size_t)(1024 + d4 + e) * C_ + k0 + kk] = f2bf(ks[e]);
                wqkvT[(size_t)(1088 + d4 + e) * C_ + k0 + kk] = f2bf(vs[e]);
            }
        }
    }
}

// ---------------------------------------------------------------------------
// bf16 MFMA GEMM, 64x64 tile, BK=64, global_load_lds(16) staging with
// global-side XOR chunk swizzle (R8-proven: conflict-free, loop-invariant
// read offsets). C[M][N] = A[M][K] @ Bt[N][K]^T.
// ---------------------------------------------------------------------------
template <bool F32OUT>
__global__ __launch_bounds__(256) void gemm64(const ushort* __restrict__ A,
                                              const ushort* __restrict__ Bt,
                                              void* __restrict__ Cv,
                                              int M, int N, int K) {
    __shared__ __align__(16) ushort As[64 * 64];
    __shared__ __align__(16) ushort Bs[64 * 64];

    const int tid = threadIdx.x, wave = tid >> 6, lane = tid & 63;
    const int g = lane >> 4, c = lane & 15;
    const int wr = wave >> 1, wc = wave & 1;
    const int m0 = blockIdx.y * 64, n0 = blockIdx.x * 64;

    const int lr8 = lane >> 3, lq8 = lane & 7;
    const int gchunk = (lq8 ^ lr8) * 8;
    const ushort* pa = A  + (size_t)(m0 + wave * 16 + lr8) * K + gchunk;
    const ushort* pb = Bt + (size_t)(n0 + wave * 16 + lr8) * K + gchunk;

    float4v acc[2][2] = {{{0,0,0,0},{0,0,0,0}},{{0,0,0,0},{0,0,0,0}}};

    for (int k0 = 0; k0 < K; k0 += 64) {
        #pragma unroll
        for (int t = 0; t < 2; ++t) {
            __builtin_amdgcn_global_load_lds(
                (const __attribute__((address_space(1))) void*)(pa + (size_t)t * 8 * K + k0),
                (__attribute__((address_space(3))) void*)&As[(wave * 16 + t * 8) * 64], 16, 0, 0);
            __builtin_amdgcn_global_load_lds(
                (const __attribute__((address_space(1))) void*)(pb + (size_t)t * 8 * K + k0),
                (__attribute__((address_space(3))) void*)&Bs[(wave * 16 + t * 8) * 64], 16, 0, 0);
        }
        __syncthreads();

        #pragma unroll
        for (int kk = 0; kk < 2; ++kk) {
            const int c7 = c & 7;
            short8 af0 = *(const short8*)&As[(wr * 32 + c) * 64 + ((kk * 4 + g) ^ c7) * 8];
            short8 af1 = *(const short8*)&As[(wr * 32 + 16 + c) * 64 + ((kk * 4 + g) ^ c7) * 8];
            short8 bf0 = *(const short8*)&Bs[(wc * 32 + c) * 64 + ((kk * 4 + g) ^ c7) * 8];
            short8 bf1 = *(const short8*)&Bs[(wc * 32 + 16 + c) * 64 + ((kk * 4 + g) ^ c7) * 8];
            acc[0][0] = __builtin_amdgcn_mfma_f32_16x16x32_bf16(af0, bf0, acc[0][0], 0, 0, 0);
            acc[0][1] = __builtin_amdgcn_mfma_f32_16x16x32_bf16(af0, bf1, acc[0][1], 0, 0, 0);
            acc[1][0] = __builtin_amdgcn_mfma_f32_16x16x32_bf16(af1, bf0, acc[1][0], 0, 0, 0);
            acc[1][1] = __builtin_amdgcn_mfma_f32_16x16x32_bf16(af1, bf1, acc[1][1], 0, 0, 0);
        }
        __syncthreads();
    }

    #pragma unroll
    for (int a = 0; a < 2; ++a)
        #pragma unroll
        for (int bb = 0; bb < 2; ++bb)
            #pragma unroll
            for (int r = 0; r < 4; ++r) {
                int rowi = m0 + wr * 32 + a * 16 + 4 * g + r;
                int coli = n0 + wc * 32 + bb * 16 + c;
                if (F32OUT) ((float*)Cv)[(size_t)rowi * N + coli] = acc[a][bb][r];
                else ((ushort*)Cv)[(size_t)rowi * N + coli] = f2bf(acc[a][bb][r]);
            }
}

// ---------------------------------------------------------------------------
// rope_kv: qkvb cols 1024..1087 = Khat, 1088..1151 = Vhat (already g-summed).
// Kt[b][j][d] = rope(Khat); VtT[b][d][j] = Vhat (bf16 pass-through).
// ---------------------------------------------------------------------------
__global__ void rope_kv(const ushort* __restrict__ qkvb,
                        ushort* __restrict__ Kt, ushort* __restrict__ VtT) {
    const int wid = threadIdx.x >> 6, d = threadIdx.x & 63;
    const int rowg = blockIdx.x * 4 + wid;          // b*N + n
    const int n = rowg & (N_ - 1), b = rowg >> 11;

    const ushort* base = qkvb + (size_t)rowg * QKV_N + 1024;
    float ks = bf2f(base[d]);
    float partner = __shfl_xor(ks, 32, 64);
    float rh = (d < 32) ? -partner : partner;
    float ang = (float)n * __powf(10000.0f, -(float)(d & 31) * (1.0f / 32.0f));
    float sn, cs; __sincosf(ang, &sn, &cs);

    Kt[(size_t)rowg * 64 + d] = f2bf(ks * cs + rh * sn);
    VtT[((size_t)b * 64 + d) * N_ + n] = base[64 + d];
}

// ---------------------------------------------------------------------------
// Flash attention v9 == attn7 (best measured: 66 us, 1.05M conflicts) with
// hoisted inv-freqs and QKV_N row stride. S^T scheme: PV via 16x16x16 with
// zero LDS traffic for P; XOR-swizzled K/V LDS; register staging; K-split x2.
// ---------------------------------------------------------------------------
#define QSCALE 0.18033688011112042f   // 0.125 * log2(e)

__global__ __launch_bounds__(256) void attn9(
        const ushort* __restrict__ qkvb, const ushort* __restrict__ Kt,
        const ushort* __restrict__ VtT,
        ushort* __restrict__ oP0, ushort* __restrict__ oP1,
        float* __restrict__ lP0, float* __restrict__ lP1) {
    const int s  = blockIdx.x & 1;
    const int qt = (blockIdx.x >> 1) & 7;
    const int h  = (blockIdx.x >> 4) & 15;
    const int b  = blockIdx.x >> 8;
    const int tid = threadIdx.x, wave = tid >> 6, lane = tid & 63;
    const int g = lane >> 4, c = lane & 15;

    __shared__ __align__(16) ushort Ksh[64 * 64];   // [j-local][d], XOR-swizzled
    __shared__ __align__(16) ushort Vsh[64 * 64];   // [d][j-local], XOR-swizzled

    ushort* oPs = s ? oP1 : oP0;
    float*  lPs = s ? lP1 : lP0;

    const int i0 = qt * 256 + wave * 64;
    float invf[8];
    #pragma unroll
    for (int i = 0; i < 8; ++i)
        invf[i] = __powf(10000.0f, -(float)(8 * g + i) * (1.0f / 32.0f));

    short8 qf[4][2];
    #pragma unroll
    for (int a = 0; a < 4; ++a) {
        const int row = i0 + a * 16 + c;
        const ushort* qrow = qkvb + (size_t)(b * N_ + row) * QKV_N + h * 64;
        short8 raw0 = *(const short8*)(qrow + 8 * g);
        short8 raw1 = *(const short8*)(qrow + 32 + 8 * g);
        #pragma unroll
        for (int i = 0; i < 8; ++i) {
            float f0 = bf2f((ushort)raw0[i]), f1 = bf2f((ushort)raw1[i]);
            float sn, cs; __sincosf((float)row * invf[i], &sn, &cs);
            qf[a][0][i] = (short)f2bf((f0 * cs - f1 * sn) * QSCALE);
            qf[a][1][i] = (short)f2bf((f1 * cs + f0 * sn) * QSCALE);
        }
    }

    float4v o[4][4];
    #pragma unroll
    for (int a = 0; a < 4; ++a)
        #pragma unroll
        for (int f = 0; f < 4; ++f) o[a][f] = {0, 0, 0, 0};
    float ll[4] = {0.f, 0.f, 0.f, 0.f};

    const ushort* Kb = Kt  + (size_t)b * N_ * 64;
    const ushort* Vb = VtT + (size_t)b * 64 * N_;
    const int lr8 = lane >> 3, lq8 = lane & 7;
    const int wpos = (lq8 ^ lr8) * 8;
    const int j0 = s * (N_ / 2);
    const int NT = (N_ / 2) / 64;

    short8 kr0 = *(const short8*)(Kb + (size_t)(j0 + wave * 16 + lr8) * 64 + lq8 * 8);
    short8 kr1 = *(const short8*)(Kb + (size_t)(j0 + wave * 16 + 8 + lr8) * 64 + lq8 * 8);
    short8 vr0 = *(const short8*)(Vb + (size_t)(wave * 16 + lr8) * N_ + j0 + lq8 * 8);
    short8 vr1 = *(const short8*)(Vb + (size_t)(wave * 16 + 8 + lr8) * N_ + j0 + lq8 * 8);

    for (int t = 0; t < NT; ++t) {
        __syncthreads();
        *(short8*)&Ksh[(wave * 16 + lr8) * 64 + wpos]     = kr0;
        *(short8*)&Ksh[(wave * 16 + 8 + lr8) * 64 + wpos] = kr1;
        *(short8*)&Vsh[(wave * 16 + lr8) * 64 + wpos]     = vr0;
        *(short8*)&Vsh[(wave * 16 + 8 + lr8) * 64 + wpos] = vr1;
        __syncthreads();
        if (t + 1 < NT) {
            const int jn = j0 + (t + 1) * 64;
            kr0 = *(const short8*)(Kb + (size_t)(jn + wave * 16 + lr8) * 64 + lq8 * 8);
            kr1 = *(const short8*)(Kb + (size_t)(jn + wave * 16 + 8 + lr8) * 64 + lq8 * 8);
            vr0 = *(const short8*)(Vb + (size_t)(wave * 16 + lr8) * N_ + jn + lq8 * 8);
            vr1 = *(const short8*)(Vb + (size_t)(wave * 16 + 8 + lr8) * N_ + jn + lq8 * 8);
        }

        #pragma unroll
        for (int jt4 = 0; jt4 < 4; ++jt4) {
            const int R = jt4 * 16 + c;
            short8 kf0 = *(const short8*)&Ksh[R * 64 + ((g ^ (c & 7)) * 8)];
            short8 kf1 = *(const short8*)&Ksh[R * 64 + (((g ^ 4) ^ (c & 7)) * 8)];
            short4v vf[4];
            #pragma unroll
            for (int f = 0; f < 4; ++f)
                vf[f] = *(const short4v*)&Vsh[(16 * f + c) * 64 +
                          (((jt4 * 2 + (g >> 1)) ^ (c & 7)) * 8) + (g & 1) * 4];

            #pragma unroll
            for (int a = 0; a < 4; ++a) {
                float4v st = {0, 0, 0, 0};
                st = __builtin_amdgcn_mfma_f32_16x16x32_bf16(kf0, qf[a][0], st, 0, 0, 0);
                st = __builtin_amdgcn_mfma_f32_16x16x32_bf16(kf1, qf[a][1], st, 0, 0, 0);
                float p0 = fexp2(st[0]), p1 = fexp2(st[1]);
                float p2 = fexp2(st[2]), p3 = fexp2(st[3]);
                ll[a] += (p0 + p1) + (p2 + p3);
                union { unsigned u[2]; short4v v; } pk;
                pk.u[0] = pack_bf16(p0, p1);
                pk.u[1] = pack_bf16(p2, p3);
                #pragma unroll
                for (int f = 0; f < 4; ++f)
                    o[a][f] = MFMA16K16(vf[f], pk.v, o[a][f]);
            }
        }
    }

    #pragma unroll
    for (int a = 0; a < 4; ++a) {
        float lt = ll[a];
        lt += __shfl_xor(lt, 16, 64);
        lt += __shfl_xor(lt, 32, 64);
        const int row = i0 + a * 16 + c;
        if (g == 0) lPs[(size_t)(b * N_ + row) * 16 + h] = lt;
        #pragma unroll
        for (int f = 0; f < 4; ++f) {
            ushort4 w;
            w.x = f2bf(o[a][f][0]); w.y = f2bf(o[a][f][1]);
            w.z = f2bf(o[a][f][2]); w.w = f2bf(o[a][f][3]);
            *(ushort4*)(oPs + (size_t)(b * N_ + row) * 1024 + h * 64 + 16 * f + 4 * g) = w;
        }
    }
}

// ---------------------------------------------------------------------------
// Combine: ao = (oP0 + oP1) / (lP0 + lP1), bf16 out (in-place over oP0 ok)
// ---------------------------------------------------------------------------
__global__ void combine(const ushort* __restrict__ oP0, const ushort* __restrict__ oP1,
                        const float* __restrict__ lP0, const float* __restrict__ lP1,
                        ushort* __restrict__ ao) {
    const int e = (blockIdx.x * 256 + threadIdx.x) * 4;
    const int row = e >> 10, hh = (e >> 6) & 15;
    const float inv = 1.0f / (lP0[row * 16 + hh] + lP1[row * 16 + hh]);
    ushort4 a = *(const ushort4*)(oP0 + e);
    ushort4 b = *(const ushort4*)(oP1 + e);
    ushort4 r;
    r.x = f2bf((bf2f(a.x) + bf2f(b.x)) * inv);
    r.y = f2bf((bf2f(a.y) + bf2f(b.y)) * inv);
    r.z = f2bf((bf2f(a.z) + bf2f(b.z)) * inv);
    r.w = f2bf((bf2f(a.w) + bf2f(b.w)) * inv);
    *(ushort4*)(ao + e) = r;
}

// ---------------------------------------------------------------------------
extern "C" void kernel_launch(void* const* d_in, const int* in_sizes, int n_in,
                              void* d_out, int out_size, void* d_ws, size_t ws_size,
                              hipStream_t stream) {
    const float* x     = (const float*)d_in[0];
    const float* w_q   = (const float*)d_in[1];
    const float* w_kv  = (const float*)d_in[2];
    const float* w_out = (const float*)d_in[3];
    float* out = (float*)d_out;

    const int M = B_ * N_;                               // 4096
    ushort* xb    = (ushort*)d_ws;                       // 4096*1024  (-> oP0 -> ao)
    ushort* wqkvT = xb    + (size_t)M * C_;              // 1152*1024
    ushort* woutT = wqkvT + (size_t)QKV_N * C_;          // 1024*1024
    ushort* qkvb  = woutT + (size_t)C_ * C_;             // 4096*1152
    ushort* Kt    = qkvb  + (size_t)M * QKV_N;           // 2*2048*64
    ushort* VtT   = Kt    + (size_t)B_ * N_ * D_;        // 2*64*2048
    ushort* oP1   = VtT   + (size_t)B_ * D_ * N_;        // 4096*1024 bf16 partial
    float*  lP0   = (float*)(oP1 + (size_t)M * C_);      // 4096*16 fp32
    float*  lP1   = lP0 + (size_t)M * H_;
    ushort* oP0   = xb;   // xb dead after qkv GEMM
    ushort* ao    = xb;   // combine writes in-place over oP0

    prep<<<4624, 256, 0, stream>>>(x, w_q, w_kv, w_out, xb, wqkvT, woutT);
    gemm64<false><<<dim3(QKV_N / 64, M / 64), 256, 0, stream>>>(xb, wqkvT, qkvb, M, QKV_N, C_);
    rope_kv<<<M / 4, 256, 0, stream>>>(qkvb, Kt, VtT);
    attn9<<<B_ * H_ * (N_ / 256) * 2, 256, 0, stream>>>(qkvb, Kt, VtT, oP0, oP1, lP0, lP1);
    combine<<<(M * C_) / 1024, 256, 0, stream>>>(oP0, oP1, lP0, lP1, ao);
    gemm64<true><<<dim3(C_ / 64, M / 64), 256, 0, stream>>>(ao, woutT, out, M, C_, C_);
}